// Round 7
// baseline (235.067 us; speedup 1.0000x reference)
//
#include <hip/hip_runtime.h>
#include <math.h>

typedef _Float16 f16;
typedef _Float16 f16x8 __attribute__((ext_vector_type(8)));
typedef _Float16 f16x4 __attribute__((ext_vector_type(4)));
typedef float f32x4 __attribute__((ext_vector_type(4)));

#define NROWS 12288
#define NFEAT 4096
#define DDIM  256
#define KDIM  1000
#define KPAD  1024
#define NSLAB 8

// workspace layout (bytes)
static const size_t OFF_BF  = 0;          // 1024*256 f16  =    524,288
static const size_t OFF_E16 = 524288;     // 12288*1024 f16= 25,165,824
static const size_t OFF_SL  = 25690112;   // 3 * 8 * 1024 f32 slabs

__device__ inline float wsum(float v) {
#pragma unroll
    for (int m = 32; m >= 1; m >>= 1) v += __shfl_xor(v, m, 64);
    return v;
}

// ---------------------------------------------------------------------------
// prep (56 blocks): [0,32)  head -> transposed normalized f16 Bf (8 k/block)
//                   [32,56) zero the 3 colsum slab sets
__global__ __launch_bounds__(256)
void prep_k(const float* __restrict__ head, f16* __restrict__ Bf,
            float* __restrict__ slabs) {
    int b = blockIdx.x, tid = threadIdx.x;
    int wave = tid >> 6, lane = tid & 63;
    if (b < 32) {
        __shared__ float rin[8];
        int kb = b * 8;
        for (int j = 0; j < 2; ++j) {
            int k = kb + wave * 2 + j;
            const float* hr = head + (size_t)k * KDIM;
            float s = 0.f;
            for (int n = lane; n < KDIM; n += 64) { float v = hr[n]; s += v * v; }
            s = wsum(s);
            if (lane == 0) rin[wave * 2 + j] = 1.0f / sqrtf(fmaxf(s, 1e-24f));
        }
        __syncthreads();
        float r[8];
#pragma unroll
        for (int i = 0; i < 8; ++i) r[i] = rin[i];
        for (int n = tid; n < KDIM; n += 256) {
            f16 tmp[8];
#pragma unroll
            for (int i = 0; i < 8; ++i)
                tmp[i] = (f16)(head[(size_t)(kb + i) * KDIM + n] * r[i]);
            *(uint4*)(Bf + (size_t)n * DDIM + kb) = *(const uint4*)(tmp);
        }
    } else {
        float* dst = slabs + (size_t)(b - 32) * KPAD + tid * 4;
        *(float4*)dst = make_float4(0.f, 0.f, 0.f, 0.f);
    }
}

// ---------------------------------------------------------------------------
// MFMA GEMM, ZERO-BARRIER K-loop: A fragments are loaded DIRECTLY from
// feats/queue f32 in MFMA layout (lane lm = row, q*8 k-slice = 32B contiguous
// per lane) and converted f32->f16 in registers -- no LDS staging, no
// per-tile __syncthreads, no serialized load latency (round-4/5's barrier
// exposed the full load latency 8x per block). A is read 2x (wave pairs
// share rows; L2-hit after the XCD swizzle). A(f32) and B(f16) are register
// double-buffered one tile ahead; all buffer indices compile-time (full
// unroll). Row sumsq accumulates on the loaded f32 values; the row-norm is
// applied in the epilogue (commutes with the dot product).
// XCD swizzle by=b%96 (a panel's 8 blocks share b%8 -> one XCD's L2 copy).
__global__ __launch_bounds__(256, 3)
void gemm_exp_k(const float* __restrict__ feats, const float* __restrict__ queue,
                const f16* __restrict__ Bf, f16* __restrict__ E16,
                float* __restrict__ S0sl) {
    __shared__ __align__(16) char smem[34816];
    f16 (*Es)[136] = (f16(*)[136])smem;
    const int tid = threadIdx.x;
    const int wave = tid >> 6, lane = tid & 63;
    const int lm = lane & 15, q = lane >> 4;
    const int b = blockIdx.x;
    const int by = b % 96, bx = b / 96;        // XCD-locality swizzle
    const int row0 = by * 128, col0 = bx * 128;
    const int wm = (wave >> 1) * 64, wn = (wave & 1) * 64;

    // block rows all come from one array: 4096 % 128 == 0
    const float* abase = (row0 < NFEAT) ? feats + (size_t)row0 * DDIM
                                        : queue + (size_t)(row0 - NFEAT) * DDIM;
    // per-lane A row pointers (MFMA fragment layout), k-offset q*8
    const float* ap[4];
#pragma unroll
    for (int ms = 0; ms < 4; ++ms)
        ap[ms] = abase + (size_t)(wm + ms * 16 + lm) * DDIM + q * 8;

    const f16* Bb = Bf + (size_t)(col0 + wn + lm) * DDIM + q * 8;

    f32x4 acc[4][4];
#pragma unroll
    for (int i = 0; i < 4; ++i)
#pragma unroll
        for (int j = 0; j < 4; ++j) acc[i][j] = (f32x4){0.f, 0.f, 0.f, 0.f};

    float ss[4] = {0.f, 0.f, 0.f, 0.f};

    // register double buffers (all indices static under full unroll)
    float4 af[2][4][2];
    f16x8  bf[2][4];
#pragma unroll
    for (int ms = 0; ms < 4; ++ms) {
        af[0][ms][0] = *(const float4*)(ap[ms]);
        af[0][ms][1] = *(const float4*)(ap[ms] + 4);
    }
#pragma unroll
    for (int ns = 0; ns < 4; ++ns)
        bf[0][ns] = *(const f16x8*)(Bb + (size_t)ns * 16 * DDIM);

#pragma unroll
    for (int t = 0; t < 8; ++t) {
        const int cur = t & 1, nxt = (t + 1) & 1;
        // issue next-tile loads first (latency hides under cvt+MFMA)
        if (t < 7) {
#pragma unroll
            for (int ns = 0; ns < 4; ++ns)
                bf[nxt][ns] = *(const f16x8*)(Bb + (size_t)ns * 16 * DDIM + (t + 1) * 32);
#pragma unroll
            for (int ms = 0; ms < 4; ++ms) {
                af[nxt][ms][0] = *(const float4*)(ap[ms] + (t + 1) * 32);
                af[nxt][ms][1] = *(const float4*)(ap[ms] + (t + 1) * 32 + 4);
            }
        }
        // cvt current A tile to f16 fragments + sumsq (VALU, overlaps MFMA pipe)
        f16x8 a8[4];
#pragma unroll
        for (int ms = 0; ms < 4; ++ms) {
            float4 u = af[cur][ms][0], v = af[cur][ms][1];
            ss[ms] += u.x * u.x + u.y * u.y + u.z * u.z + u.w * u.w
                    + v.x * v.x + v.y * v.y + v.z * v.z + v.w * v.w;
            a8[ms] = (f16x8){ (f16)u.x, (f16)u.y, (f16)u.z, (f16)u.w,
                              (f16)v.x, (f16)v.y, (f16)v.z, (f16)v.w };
        }
#pragma unroll
        for (int ms = 0; ms < 4; ++ms)
#pragma unroll
            for (int ns = 0; ns < 4; ++ns)
                acc[ms][ns] = __builtin_amdgcn_mfma_f32_16x16x32_f16(a8[ms], bf[cur][ns], acc[ms][ns], 0, 0, 0);
    }

    // ---- row inverse norms: lane's partial covers k in {t*32+q*8..+8};
    // the 4 q-lanes sharing lm partition k fully -> reduce over lane^16,^32.
#pragma unroll
    for (int ms = 0; ms < 4; ++ms) {
        ss[ms] += __shfl_xor(ss[ms], 16, 64);
        ss[ms] += __shfl_xor(ss[ms], 32, 64);
    }
    // epilogue rows for this lane are q*4+rr (not lm): fetch via shfl from
    // lane (q*4+rr), whose lm equals that row (q-group 0 copy).
    float rsc[4][4];
#pragma unroll
    for (int ms = 0; ms < 4; ++ms)
#pragma unroll
        for (int rr = 0; rr < 4; ++rr) {
            float s4 = __shfl(ss[ms], q * 4 + rr, 64);
            rsc[ms][rr] = 20.0f / sqrtf(fmaxf(s4, 1e-24f));
        }

    // ---- exp + Es + colsum partials (proven epilogue; per-row scale)
    float colp[4] = {0.f, 0.f, 0.f, 0.f};
#pragma unroll
    for (int ms = 0; ms < 4; ++ms) {
#pragma unroll
        for (int ns = 0; ns < 4; ++ns) {
            int gc = col0 + wn + ns * 16 + lm;
            bool ok = gc < KDIM;
#pragma unroll
            for (int rr = 0; rr < 4; ++rr) {
                float e = ok ? __expf(acc[ms][ns][rr] * rsc[ms][rr]) : 0.0f;
                colp[ns] += e;
                Es[wm + ms * 16 + q * 4 + rr][wn + ns * 16 + lm] = (f16)e;
            }
        }
    }
#pragma unroll
    for (int ns = 0; ns < 4; ++ns) {
        colp[ns] += __shfl_xor(colp[ns], 16, 64);
        colp[ns] += __shfl_xor(colp[ns], 32, 64);
    }
    __syncthreads();
    {
        int rr = tid >> 1, half = tid & 1;
        const f16* src = &Es[rr][half * 64];
        f16* dst = E16 + (size_t)(row0 + rr) * KPAD + col0 + half * 64;
#pragma unroll
        for (int i = 0; i < 8; ++i)
            *(uint4*)(dst + i * 8) = *(const uint4*)(src + i * 8);
    }
    __syncthreads();
    float* cred = (float*)smem;
    if (tid < 128) cred[tid] = 0.f;
    __syncthreads();
    if (lane < 16) {
#pragma unroll
        for (int ns = 0; ns < 4; ++ns)
            atomicAdd(&cred[wn + ns * 16 + lane], colp[ns]);   // LDS atomic
    }
    __syncthreads();
    if (tid < 128)
        atomicAdd(&S0sl[(size_t)(by & 7) * KPAD + col0 + tid], cred[tid]);
}

// ---------------------------------------------------------------------------
// rowpass: XCD-aligned block remap. gemm panel p was written by XCD p%8;
// block bid (XCD bid%8) reads strip st of a panel p with p%8 == bid%8, so
// E reads hit the local L2 instead of crossing XCDs. Bijective:
// (x, i%12, i/12) <-> (p, st), 8*12*8 = 768.
__global__ __launch_bounds__(256)
void rowpass_k(const f16* __restrict__ E16, const float* __restrict__ SinSl,
               float* __restrict__ SoutSl) {
    __shared__ float rl[KPAD];
    __shared__ float cols4[4][KPAD];
    int tid = threadIdx.x, bid = blockIdx.x;
    {
        int n = tid * 4;
        float4 s = *(const float4*)(SinSl + n);
#pragma unroll
        for (int j = 1; j < NSLAB; ++j) {
            float4 t = *(const float4*)(SinSl + (size_t)j * KPAD + n);
            s.x += t.x; s.y += t.y; s.z += t.z; s.w += t.w;
        }
        float4 o;
        o.x = (n + 0 < KDIM) ? 1.0f / (1000.0f * s.x) : 0.0f;
        o.y = (n + 1 < KDIM) ? 1.0f / (1000.0f * s.y) : 0.0f;
        o.z = (n + 2 < KDIM) ? 1.0f / (1000.0f * s.z) : 0.0f;
        o.w = (n + 3 < KDIM) ? 1.0f / (1000.0f * s.w) : 0.0f;
        *(float4*)(rl + n) = o;
    }
    __syncthreads();
    int wave = tid >> 6, lane = tid & 63;
    int n0 = lane * 16;
    float rv[16];
#pragma unroll
    for (int i = 0; i < 16; ++i) rv[i] = rl[n0 + i];

    int x = bid & 7, ii = bid >> 3;
    int p = x + 8 * (ii % 12);            // panel [0,96), p%8 == x
    int st = ii / 12;                     // strip [0,8)
    int rowbase = p * 128 + st * 16 + wave * 4;
    const f16* erb = E16 + (size_t)rowbase * KPAD + n0;
    f16x8 e[4][2];
#pragma unroll
    for (int j = 0; j < 4; ++j) {
        e[j][0] = *(const f16x8*)(erb + (size_t)j * KPAD);
        e[j][1] = *(const f16x8*)(erb + (size_t)j * KPAD + 8);
    }
    float pr[4];
#pragma unroll
    for (int j = 0; j < 4; ++j) {
        float acc = 0.f;
#pragma unroll
        for (int i = 0; i < 8; ++i) {
            acc += (float)e[j][0][i] * rv[i];
            acc += (float)e[j][1][i] * rv[8 + i];
        }
        pr[j] = acc;
    }
#pragma unroll
    for (int m = 32; m >= 1; m >>= 1) {
        float t0 = __shfl_xor(pr[0], m, 64);
        float t1 = __shfl_xor(pr[1], m, 64);
        float t2 = __shfl_xor(pr[2], m, 64);
        float t3 = __shfl_xor(pr[3], m, 64);
        pr[0] += t0; pr[1] += t1; pr[2] += t2; pr[3] += t3;
    }
    float c[4];
#pragma unroll
    for (int j = 0; j < 4; ++j) c[j] = 1.0f / (12288.0f * pr[j]);
    float ca[16];
#pragma unroll
    for (int i = 0; i < 16; ++i) {
        int h = i >> 3, iv = i & 7;
        ca[i] = (float)e[0][h][iv] * c[0] + (float)e[1][h][iv] * c[1]
              + (float)e[2][h][iv] * c[2] + (float)e[3][h][iv] * c[3];
    }
#pragma unroll
    for (int i = 0; i < 16; ++i) {
        int idx = (i + lane) & 15;
        cols4[wave][n0 + idx] = ca[idx];
    }
    __syncthreads();
    float* outSlab = SoutSl + (size_t)x * KPAD;
    for (int n = tid; n < KPAD; n += 256)
        atomicAdd(&outSlab[n],
                  cols4[0][n] + cols4[1][n] + cols4[2][n] + cols4[3][n]);
}

// ---------------------------------------------------------------------------
// out: XCD-aligned remap over the 32 feats panels: (x, i%4, i/4) <-> (p, st),
// 8*4*32 = 1024 blocks, 4 rows each.
__global__ __launch_bounds__(256)
void out_k(const f16* __restrict__ E16, const float* __restrict__ S2sl,
           float* __restrict__ out) {
    __shared__ float rl[KPAD];
    int tid = threadIdx.x;
    {
        int n = tid * 4;
        float4 s = *(const float4*)(S2sl + n);
#pragma unroll
        for (int j = 1; j < NSLAB; ++j) {
            float4 t = *(const float4*)(S2sl + (size_t)j * KPAD + n);
            s.x += t.x; s.y += t.y; s.z += t.z; s.w += t.w;
        }
        float4 o;
        o.x = (n + 0 < KDIM) ? 1.0f / (1000.0f * s.x) : 0.0f;
        o.y = (n + 1 < KDIM) ? 1.0f / (1000.0f * s.y) : 0.0f;
        o.z = (n + 2 < KDIM) ? 1.0f / (1000.0f * s.z) : 0.0f;
        o.w = (n + 3 < KDIM) ? 1.0f / (1000.0f * s.w) : 0.0f;
        *(float4*)(rl + n) = o;
    }
    __syncthreads();
    int wave = tid >> 6, lane = tid & 63;
    int n0 = lane * 16;
    float rv[16];
#pragma unroll
    for (int i = 0; i < 16; ++i) rv[i] = rl[n0 + i];
    int bid = blockIdx.x;
    int x = bid & 7, ii = bid >> 3;
    int p = x + 8 * (ii % 4);             // panel [0,32), p%8 == x
    int st = ii / 4;                      // [0,32)
    int row = p * 128 + st * 4 + wave;
    const f16* er = E16 + (size_t)row * KPAD + n0;
    f16x8 e0 = *(const f16x8*)er;
    f16x8 e1 = *(const f16x8*)(er + 8);
    float w[16];
    float pv = 0.f;
#pragma unroll
    for (int i = 0; i < 8; ++i) {
        w[i] = (float)e0[i] * rv[i];
        w[8 + i] = (float)e1[i] * rv[8 + i];
    }
#pragma unroll
    for (int i = 0; i < 16; ++i) pv += w[i];
    pv = wsum(pv);
    float inv = 1.0f / pv;
    float* orow = out + (size_t)row * KDIM;
#pragma unroll
    for (int i = 0; i < 16; i += 4) {
        int n = n0 + i;
        if (n + 3 < KDIM) {   // KDIM%4==0: quad fully valid or fully out
            float4 o = { w[i] * inv, w[i + 1] * inv, w[i + 2] * inv, w[i + 3] * inv };
            *(float4*)(orow + n) = o;
        }
    }
}

// ---------------------------------------------------------------------------
extern "C" void kernel_launch(void* const* d_in, const int* in_sizes, int n_in,
                              void* d_out, int out_size, void* d_ws, size_t ws_size,
                              hipStream_t stream) {
    (void)in_sizes; (void)n_in; (void)out_size; (void)ws_size;
    const float* feats = (const float*)d_in[0];   // [4096,256]
    const float* head  = (const float*)d_in[1];   // [256,1000]
    const float* queue = (const float*)d_in[2];   // [8192,256]
    float* out = (float*)d_out;                   // [4096,1000]

    char* ws = (char*)d_ws;
    f16*   Bf    = (f16*)(ws + OFF_BF);
    f16*   E16   = (f16*)(ws + OFF_E16);
    float* slabs = (float*)(ws + OFF_SL);
    float* S0sl  = slabs;
    float* S1sl  = slabs + NSLAB * KPAD;
    float* S2sl  = slabs + 2 * NSLAB * KPAD;

    prep_k<<<56, 256, 0, stream>>>(head, Bf, slabs);
    gemm_exp_k<<<768, 256, 0, stream>>>(feats, queue, Bf, E16, S0sl);
    rowpass_k<<<768, 256, 0, stream>>>(E16, S0sl, S1sl);
    rowpass_k<<<768, 256, 0, stream>>>(E16, S1sl, S2sl);
    out_k<<<1024, 256, 0, stream>>>(E16, S2sl, out);
}

// Round 8
// 165.338 us; speedup vs baseline: 1.4217x; 1.4217x over previous
//
#include <hip/hip_runtime.h>
#include <math.h>

typedef _Float16 f16;
typedef _Float16 f16x8 __attribute__((ext_vector_type(8)));
typedef _Float16 f16x4 __attribute__((ext_vector_type(4)));
typedef float f32x4 __attribute__((ext_vector_type(4)));

#define NROWS 12288
#define NFEAT 4096
#define DDIM  256
#define KDIM  1000
#define KPAD  1024
#define NSLAB 8

// workspace layout (bytes)
static const size_t OFF_BF  = 0;          // 1024*256 f16  =    524,288
static const size_t OFF_E16 = 524288;     // 12288*1024 f16= 25,165,824
static const size_t OFF_SL  = 25690112;   // 3 * 8 * 1024 f32 slabs

__device__ inline float wsum(float v) {
#pragma unroll
    for (int m = 32; m >= 1; m >>= 1) v += __shfl_xor(v, m, 64);
    return v;
}

// ---------------------------------------------------------------------------
// prep (56 blocks): [0,32)  head -> transposed normalized f16 Bf (8 k/block)
//                   [32,56) zero the 3 colsum slab sets
__global__ __launch_bounds__(256)
void prep_k(const float* __restrict__ head, f16* __restrict__ Bf,
            float* __restrict__ slabs) {
    int b = blockIdx.x, tid = threadIdx.x;
    int wave = tid >> 6, lane = tid & 63;
    if (b < 32) {
        __shared__ float rin[8];
        int kb = b * 8;
        for (int j = 0; j < 2; ++j) {
            int k = kb + wave * 2 + j;
            const float* hr = head + (size_t)k * KDIM;
            float s = 0.f;
            for (int n = lane; n < KDIM; n += 64) { float v = hr[n]; s += v * v; }
            s = wsum(s);
            if (lane == 0) rin[wave * 2 + j] = 1.0f / sqrtf(fmaxf(s, 1e-24f));
        }
        __syncthreads();
        float r[8];
#pragma unroll
        for (int i = 0; i < 8; ++i) r[i] = rin[i];
        for (int n = tid; n < KDIM; n += 256) {
            f16 tmp[8];
#pragma unroll
            for (int i = 0; i < 8; ++i)
                tmp[i] = (f16)(head[(size_t)(kb + i) * KDIM + n] * r[i]);
            *(uint4*)(Bf + (size_t)n * DDIM + kb) = *(const uint4*)(tmp);
        }
    } else {
        float* dst = slabs + (size_t)(b - 32) * KPAD + tid * 4;
        *(float4*)dst = make_float4(0.f, 0.f, 0.f, 0.f);
    }
}

// ---------------------------------------------------------------------------
// MFMA GEMM, ZERO-BARRIER K-loop (round-7 structure, verified correct):
// A fragments loaded DIRECTLY from feats/queue f32 in MFMA layout, cvt in
// registers, A+B register double-buffered one tile ahead; row-norm folded
// into the epilogue via shfl-reduced sumsq.
// ROUND-8 FIX: __launch_bounds__(256, 2), not (256, 3). The (256,3) pledge
// capped the allocator at ~168 VGPR/wave while the working set (af 64 f32
// regs + bf 32 + acc 64 on the unified VGPR/AGPR file + addressing) needs
// ~208 -> massive scratch spill (r7 counters: 150 MB FETCH / 296 MB WRITE,
// 12x traffic budget, HBM-bound at 44% peak on its own spill). At 2 waves/EU
// the budget is 256 VGPR: fits, no spill. Latency hiding here is register
// double-buffer ILP, not TLP, so 2 blocks/CU suffices.
// XCD swizzle by=b%96 (a panel's 8 blocks share b%8 -> one XCD's L2 copy).
__global__ __launch_bounds__(256, 2)
void gemm_exp_k(const float* __restrict__ feats, const float* __restrict__ queue,
                const f16* __restrict__ Bf, f16* __restrict__ E16,
                float* __restrict__ S0sl) {
    __shared__ __align__(16) char smem[34816];
    f16 (*Es)[136] = (f16(*)[136])smem;
    const int tid = threadIdx.x;
    const int wave = tid >> 6, lane = tid & 63;
    const int lm = lane & 15, q = lane >> 4;
    const int b = blockIdx.x;
    const int by = b % 96, bx = b / 96;        // XCD-locality swizzle
    const int row0 = by * 128, col0 = bx * 128;
    const int wm = (wave >> 1) * 64, wn = (wave & 1) * 64;

    // block rows all come from one array: 4096 % 128 == 0
    const float* abase = (row0 < NFEAT) ? feats + (size_t)row0 * DDIM
                                        : queue + (size_t)(row0 - NFEAT) * DDIM;
    // per-lane A row pointers (MFMA fragment layout), k-offset q*8
    const float* ap[4];
#pragma unroll
    for (int ms = 0; ms < 4; ++ms)
        ap[ms] = abase + (size_t)(wm + ms * 16 + lm) * DDIM + q * 8;

    const f16* Bb = Bf + (size_t)(col0 + wn + lm) * DDIM + q * 8;

    f32x4 acc[4][4];
#pragma unroll
    for (int i = 0; i < 4; ++i)
#pragma unroll
        for (int j = 0; j < 4; ++j) acc[i][j] = (f32x4){0.f, 0.f, 0.f, 0.f};

    float ss[4] = {0.f, 0.f, 0.f, 0.f};

    // register double buffers (all indices static under full unroll)
    float4 af[2][4][2];
    f16x8  bf[2][4];
#pragma unroll
    for (int ms = 0; ms < 4; ++ms) {
        af[0][ms][0] = *(const float4*)(ap[ms]);
        af[0][ms][1] = *(const float4*)(ap[ms] + 4);
    }
#pragma unroll
    for (int ns = 0; ns < 4; ++ns)
        bf[0][ns] = *(const f16x8*)(Bb + (size_t)ns * 16 * DDIM);

#pragma unroll
    for (int t = 0; t < 8; ++t) {
        const int cur = t & 1, nxt = (t + 1) & 1;
        // issue next-tile loads first (latency hides under cvt+MFMA)
        if (t < 7) {
#pragma unroll
            for (int ns = 0; ns < 4; ++ns)
                bf[nxt][ns] = *(const f16x8*)(Bb + (size_t)ns * 16 * DDIM + (t + 1) * 32);
#pragma unroll
            for (int ms = 0; ms < 4; ++ms) {
                af[nxt][ms][0] = *(const float4*)(ap[ms] + (t + 1) * 32);
                af[nxt][ms][1] = *(const float4*)(ap[ms] + (t + 1) * 32 + 4);
            }
        }
        // cvt current A tile to f16 fragments + sumsq (VALU, overlaps MFMA pipe)
        f16x8 a8[4];
#pragma unroll
        for (int ms = 0; ms < 4; ++ms) {
            float4 u = af[cur][ms][0], v = af[cur][ms][1];
            ss[ms] += u.x * u.x + u.y * u.y + u.z * u.z + u.w * u.w
                    + v.x * v.x + v.y * v.y + v.z * v.z + v.w * v.w;
            a8[ms] = (f16x8){ (f16)u.x, (f16)u.y, (f16)u.z, (f16)u.w,
                              (f16)v.x, (f16)v.y, (f16)v.z, (f16)v.w };
        }
#pragma unroll
        for (int ms = 0; ms < 4; ++ms)
#pragma unroll
            for (int ns = 0; ns < 4; ++ns)
                acc[ms][ns] = __builtin_amdgcn_mfma_f32_16x16x32_f16(a8[ms], bf[cur][ns], acc[ms][ns], 0, 0, 0);
    }

    // ---- row inverse norms: lane's partial covers k in {t*32+q*8..+8};
    // the 4 q-lanes sharing lm partition k fully -> reduce over lane^16,^32.
#pragma unroll
    for (int ms = 0; ms < 4; ++ms) {
        ss[ms] += __shfl_xor(ss[ms], 16, 64);
        ss[ms] += __shfl_xor(ss[ms], 32, 64);
    }
    // epilogue rows for this lane are q*4+rr (not lm): fetch via shfl from
    // lane (q*4+rr), whose lm equals that row (q-group 0 copy).
    float rsc[4][4];
#pragma unroll
    for (int ms = 0; ms < 4; ++ms)
#pragma unroll
        for (int rr = 0; rr < 4; ++rr) {
            float s4 = __shfl(ss[ms], q * 4 + rr, 64);
            rsc[ms][rr] = 20.0f / sqrtf(fmaxf(s4, 1e-24f));
        }

    // ---- exp + Es + colsum partials (proven epilogue; per-row scale)
    float colp[4] = {0.f, 0.f, 0.f, 0.f};
#pragma unroll
    for (int ms = 0; ms < 4; ++ms) {
#pragma unroll
        for (int ns = 0; ns < 4; ++ns) {
            int gc = col0 + wn + ns * 16 + lm;
            bool ok = gc < KDIM;
#pragma unroll
            for (int rr = 0; rr < 4; ++rr) {
                float e = ok ? __expf(acc[ms][ns][rr] * rsc[ms][rr]) : 0.0f;
                colp[ns] += e;
                Es[wm + ms * 16 + q * 4 + rr][wn + ns * 16 + lm] = (f16)e;
            }
        }
    }
#pragma unroll
    for (int ns = 0; ns < 4; ++ns) {
        colp[ns] += __shfl_xor(colp[ns], 16, 64);
        colp[ns] += __shfl_xor(colp[ns], 32, 64);
    }
    __syncthreads();
    {
        int rr = tid >> 1, half = tid & 1;
        const f16* src = &Es[rr][half * 64];
        f16* dst = E16 + (size_t)(row0 + rr) * KPAD + col0 + half * 64;
#pragma unroll
        for (int i = 0; i < 8; ++i)
            *(uint4*)(dst + i * 8) = *(const uint4*)(src + i * 8);
    }
    __syncthreads();
    float* cred = (float*)smem;
    if (tid < 128) cred[tid] = 0.f;
    __syncthreads();
    if (lane < 16) {
#pragma unroll
        for (int ns = 0; ns < 4; ++ns)
            atomicAdd(&cred[wn + ns * 16 + lane], colp[ns]);   // LDS atomic
    }
    __syncthreads();
    if (tid < 128)
        atomicAdd(&S0sl[(size_t)(by & 7) * KPAD + col0 + tid], cred[tid]);
}

// ---------------------------------------------------------------------------
// rowpass: XCD-aligned block remap. gemm panel p was written by XCD p%8;
// block bid (XCD bid%8) reads strip st of a panel p with p%8 == bid%8, so
// E reads hit the local L2 instead of crossing XCDs. Bijective:
// (x, i%12, i/12) <-> (p, st), 8*12*8 = 768.
__global__ __launch_bounds__(256)
void rowpass_k(const f16* __restrict__ E16, const float* __restrict__ SinSl,
               float* __restrict__ SoutSl) {
    __shared__ float rl[KPAD];
    __shared__ float cols4[4][KPAD];
    int tid = threadIdx.x, bid = blockIdx.x;
    {
        int n = tid * 4;
        float4 s = *(const float4*)(SinSl + n);
#pragma unroll
        for (int j = 1; j < NSLAB; ++j) {
            float4 t = *(const float4*)(SinSl + (size_t)j * KPAD + n);
            s.x += t.x; s.y += t.y; s.z += t.z; s.w += t.w;
        }
        float4 o;
        o.x = (n + 0 < KDIM) ? 1.0f / (1000.0f * s.x) : 0.0f;
        o.y = (n + 1 < KDIM) ? 1.0f / (1000.0f * s.y) : 0.0f;
        o.z = (n + 2 < KDIM) ? 1.0f / (1000.0f * s.z) : 0.0f;
        o.w = (n + 3 < KDIM) ? 1.0f / (1000.0f * s.w) : 0.0f;
        *(float4*)(rl + n) = o;
    }
    __syncthreads();
    int wave = tid >> 6, lane = tid & 63;
    int n0 = lane * 16;
    float rv[16];
#pragma unroll
    for (int i = 0; i < 16; ++i) rv[i] = rl[n0 + i];

    int x = bid & 7, ii = bid >> 3;
    int p = x + 8 * (ii % 12);            // panel [0,96), p%8 == x
    int st = ii / 12;                     // strip [0,8)
    int rowbase = p * 128 + st * 16 + wave * 4;
    const f16* erb = E16 + (size_t)rowbase * KPAD + n0;
    f16x8 e[4][2];
#pragma unroll
    for (int j = 0; j < 4; ++j) {
        e[j][0] = *(const f16x8*)(erb + (size_t)j * KPAD);
        e[j][1] = *(const f16x8*)(erb + (size_t)j * KPAD + 8);
    }
    float pr[4];
#pragma unroll
    for (int j = 0; j < 4; ++j) {
        float acc = 0.f;
#pragma unroll
        for (int i = 0; i < 8; ++i) {
            acc += (float)e[j][0][i] * rv[i];
            acc += (float)e[j][1][i] * rv[8 + i];
        }
        pr[j] = acc;
    }
#pragma unroll
    for (int m = 32; m >= 1; m >>= 1) {
        float t0 = __shfl_xor(pr[0], m, 64);
        float t1 = __shfl_xor(pr[1], m, 64);
        float t2 = __shfl_xor(pr[2], m, 64);
        float t3 = __shfl_xor(pr[3], m, 64);
        pr[0] += t0; pr[1] += t1; pr[2] += t2; pr[3] += t3;
    }
    float c[4];
#pragma unroll
    for (int j = 0; j < 4; ++j) c[j] = 1.0f / (12288.0f * pr[j]);
    float ca[16];
#pragma unroll
    for (int i = 0; i < 16; ++i) {
        int h = i >> 3, iv = i & 7;
        ca[i] = (float)e[0][h][iv] * c[0] + (float)e[1][h][iv] * c[1]
              + (float)e[2][h][iv] * c[2] + (float)e[3][h][iv] * c[3];
    }
#pragma unroll
    for (int i = 0; i < 16; ++i) {
        int idx = (i + lane) & 15;
        cols4[wave][n0 + idx] = ca[idx];
    }
    __syncthreads();
    float* outSlab = SoutSl + (size_t)x * KPAD;
    for (int n = tid; n < KPAD; n += 256)
        atomicAdd(&outSlab[n],
                  cols4[0][n] + cols4[1][n] + cols4[2][n] + cols4[3][n]);
}

// ---------------------------------------------------------------------------
// out: XCD-aligned remap over the 32 feats panels: (x, i%4, i/4) <-> (p, st),
// 8*4*32 = 1024 blocks, 4 rows each.
__global__ __launch_bounds__(256)
void out_k(const f16* __restrict__ E16, const float* __restrict__ S2sl,
           float* __restrict__ out) {
    __shared__ float rl[KPAD];
    int tid = threadIdx.x;
    {
        int n = tid * 4;
        float4 s = *(const float4*)(S2sl + n);
#pragma unroll
        for (int j = 1; j < NSLAB; ++j) {
            float4 t = *(const float4*)(S2sl + (size_t)j * KPAD + n);
            s.x += t.x; s.y += t.y; s.z += t.z; s.w += t.w;
        }
        float4 o;
        o.x = (n + 0 < KDIM) ? 1.0f / (1000.0f * s.x) : 0.0f;
        o.y = (n + 1 < KDIM) ? 1.0f / (1000.0f * s.y) : 0.0f;
        o.z = (n + 2 < KDIM) ? 1.0f / (1000.0f * s.z) : 0.0f;
        o.w = (n + 3 < KDIM) ? 1.0f / (1000.0f * s.w) : 0.0f;
        *(float4*)(rl + n) = o;
    }
    __syncthreads();
    int wave = tid >> 6, lane = tid & 63;
    int n0 = lane * 16;
    float rv[16];
#pragma unroll
    for (int i = 0; i < 16; ++i) rv[i] = rl[n0 + i];
    int bid = blockIdx.x;
    int x = bid & 7, ii = bid >> 3;
    int p = x + 8 * (ii % 4);             // panel [0,32), p%8 == x
    int st = ii / 4;                      // [0,32)
    int row = p * 128 + st * 4 + wave;
    const f16* er = E16 + (size_t)row * KPAD + n0;
    f16x8 e0 = *(const f16x8*)er;
    f16x8 e1 = *(const f16x8*)(er + 8);
    float w[16];
    float pv = 0.f;
#pragma unroll
    for (int i = 0; i < 8; ++i) {
        w[i] = (float)e0[i] * rv[i];
        w[8 + i] = (float)e1[i] * rv[8 + i];
    }
#pragma unroll
    for (int i = 0; i < 16; ++i) pv += w[i];
    pv = wsum(pv);
    float inv = 1.0f / pv;
    float* orow = out + (size_t)row * KDIM;
#pragma unroll
    for (int i = 0; i < 16; i += 4) {
        int n = n0 + i;
        if (n + 3 < KDIM) {   // KDIM%4==0: quad fully valid or fully out
            float4 o = { w[i] * inv, w[i + 1] * inv, w[i + 2] * inv, w[i + 3] * inv };
            *(float4*)(orow + n) = o;
        }
    }
}

// ---------------------------------------------------------------------------
extern "C" void kernel_launch(void* const* d_in, const int* in_sizes, int n_in,
                              void* d_out, int out_size, void* d_ws, size_t ws_size,
                              hipStream_t stream) {
    (void)in_sizes; (void)n_in; (void)out_size; (void)ws_size;
    const float* feats = (const float*)d_in[0];   // [4096,256]
    const float* head  = (const float*)d_in[1];   // [256,1000]
    const float* queue = (const float*)d_in[2];   // [8192,256]
    float* out = (float*)d_out;                   // [4096,1000]

    char* ws = (char*)d_ws;
    f16*   Bf    = (f16*)(ws + OFF_BF);
    f16*   E16   = (f16*)(ws + OFF_E16);
    float* slabs = (float*)(ws + OFF_SL);
    float* S0sl  = slabs;
    float* S1sl  = slabs + NSLAB * KPAD;
    float* S2sl  = slabs + 2 * NSLAB * KPAD;

    prep_k<<<56, 256, 0, stream>>>(head, Bf, slabs);
    gemm_exp_k<<<768, 256, 0, stream>>>(feats, queue, Bf, E16, S0sl);
    rowpass_k<<<768, 256, 0, stream>>>(E16, S0sl, S1sl);
    rowpass_k<<<768, 256, 0, stream>>>(E16, S1sl, S2sl);
    out_k<<<1024, 256, 0, stream>>>(E16, S2sl, out);
}

// Round 9
// 147.193 us; speedup vs baseline: 1.5970x; 1.1233x over previous
//
#include <hip/hip_runtime.h>
#include <math.h>

typedef _Float16 f16;
typedef _Float16 f16x8 __attribute__((ext_vector_type(8)));
typedef _Float16 f16x4 __attribute__((ext_vector_type(4)));
typedef float f32x4 __attribute__((ext_vector_type(4)));

#define NROWS 12288
#define NFEAT 4096
#define DDIM  256
#define KDIM  1000
#define KPAD  1024
#define NSLAB 8

// workspace layout (bytes)
static const size_t OFF_A16 = 0;           // 12288*256 f16 = 6,291,456
static const size_t OFF_BF  = 6291456;     // 1024*256 f16  =   524,288
static const size_t OFF_E16 = 6815744;     // 12288*1024 f16= 25,165,824
static const size_t OFF_SL  = 31981568;    // 3 * 8 * 1024 f32 slabs

__device__ inline float wsum(float v) {
#pragma unroll
    for (int m = 32; m >= 1; m >>= 1) v += __shfl_xor(v, m, 64);
    return v;
}

// ---------------------------------------------------------------------------
// prep (3128 blocks): [0,3072)   feats/queue row norms -> A16 (4 rows/block)
//                     [3072,3104) head -> transposed normalized f16 Bf
//                     [3104,3128) zero the 3 colsum slab sets
// (r0-proven; packing A16 here keeps the gemm f16-only and register-lean.)
__global__ __launch_bounds__(256)
void prep_k(const float* __restrict__ feats, const float* __restrict__ queue,
            const float* __restrict__ head, f16* __restrict__ A16,
            f16* __restrict__ Bf, float* __restrict__ slabs) {
    int b = blockIdx.x, tid = threadIdx.x;
    int wave = tid >> 6, lane = tid & 63;
    if (b < 3072) {
        int row = b * 4 + wave;
        const float* src = (row < NFEAT) ? feats + (size_t)row * DDIM
                                         : queue + (size_t)(row - NFEAT) * DDIM;
        float4 v = *(const float4*)(src + lane * 4);
        float s = wsum(v.x * v.x + v.y * v.y + v.z * v.z + v.w * v.w);
        float inv = 1.0f / sqrtf(fmaxf(s, 1e-24f));
        f16x4 o = { (f16)(v.x * inv), (f16)(v.y * inv), (f16)(v.z * inv), (f16)(v.w * inv) };
        *(f16x4*)(A16 + (size_t)row * DDIM + lane * 4) = o;
    } else if (b < 3104) {
        __shared__ float rin[8];
        int kb = (b - 3072) * 8;
        for (int j = 0; j < 2; ++j) {
            int k = kb + wave * 2 + j;
            const float* hr = head + (size_t)k * KDIM;
            float s = 0.f;
            for (int n = lane; n < KDIM; n += 64) { float v = hr[n]; s += v * v; }
            s = wsum(s);
            if (lane == 0) rin[wave * 2 + j] = 1.0f / sqrtf(fmaxf(s, 1e-24f));
        }
        __syncthreads();
        float r[8];
#pragma unroll
        for (int i = 0; i < 8; ++i) r[i] = rin[i];
        for (int n = tid; n < KDIM; n += 256) {
            f16 tmp[8];
#pragma unroll
            for (int i = 0; i < 8; ++i)
                tmp[i] = (f16)(head[(size_t)(kb + i) * KDIM + n] * r[i]);
            *(uint4*)(Bf + (size_t)n * DDIM + kb) = *(const uint4*)(tmp);
        }
    } else {
        float* dst = slabs + (size_t)(b - 3104) * KPAD + tid * 4;
        *(float4*)dst = make_float4(0.f, 0.f, 0.f, 0.f);
    }
}

// ---------------------------------------------------------------------------
// MFMA GEMM, ZERO-BARRIER K-loop on pre-packed f16 operands.
// A16/Bf fragments loaded DIRECTLY from global in MFMA layout (lane lm = row,
// q*8 f16 k-slice = 16 B contiguous; the 4 q-lane groups cover 64 B/row).
// Register double-buffer is f16-only: af[2][4]+bf[2][4] = 32 VGPRs (vs r7/r8's
// 96 with raw f32 + sumsq, which spilled ~34 MB scratch at any occupancy tier).
// Total ~130 regs -> fits the (256,3) cap of 168: no spill AND 3 blocks/CU.
// No per-tile __syncthreads: each iteration's loads retire one full MFMA
// cluster later (r0's barrier drain was its ~28 us cost).
// XCD swizzle by=b%96: a panel's 8 blocks share b%8 -> one XCD's L2 copy
// (proven r4: FETCH 48->8.4 MB).
__global__ __launch_bounds__(256, 3)
void gemm_exp_k(const f16* __restrict__ A16, const f16* __restrict__ Bf,
                f16* __restrict__ E16, float* __restrict__ S0sl) {
    __shared__ __align__(16) char smem[34816];
    f16 (*Es)[136] = (f16(*)[136])smem;
    const int tid = threadIdx.x;
    const int wave = tid >> 6, lane = tid & 63;
    const int lm = lane & 15, q = lane >> 4;
    const int b = blockIdx.x;
    const int by = b % 96, bx = b / 96;        // XCD-locality swizzle
    const int row0 = by * 128, col0 = bx * 128;
    const int wm = (wave >> 1) * 64, wn = (wave & 1) * 64;

    const f16* Ab = A16 + (size_t)(row0 + wm + lm) * DDIM + q * 8;
    const f16* Bb = Bf  + (size_t)(col0 + wn + lm) * DDIM + q * 8;

    f32x4 acc[4][4];
#pragma unroll
    for (int i = 0; i < 4; ++i)
#pragma unroll
        for (int j = 0; j < 4; ++j) acc[i][j] = (f32x4){0.f, 0.f, 0.f, 0.f};

    // f16 register double buffers (all indices static under full unroll)
    f16x8 af[2][4], bf[2][4];
#pragma unroll
    for (int ms = 0; ms < 4; ++ms) af[0][ms] = *(const f16x8*)(Ab + (size_t)ms * 16 * DDIM);
#pragma unroll
    for (int ns = 0; ns < 4; ++ns) bf[0][ns] = *(const f16x8*)(Bb + (size_t)ns * 16 * DDIM);

#pragma unroll
    for (int t = 0; t < 8; ++t) {
        const int cur = t & 1, nxt = (t + 1) & 1;
        if (t < 7) {   // issue next-tile loads; they drain during this tile's MFMAs
#pragma unroll
            for (int ms = 0; ms < 4; ++ms)
                af[nxt][ms] = *(const f16x8*)(Ab + (size_t)ms * 16 * DDIM + (t + 1) * 32);
#pragma unroll
            for (int ns = 0; ns < 4; ++ns)
                bf[nxt][ns] = *(const f16x8*)(Bb + (size_t)ns * 16 * DDIM + (t + 1) * 32);
        }
#pragma unroll
        for (int ms = 0; ms < 4; ++ms)
#pragma unroll
            for (int ns = 0; ns < 4; ++ns)
                acc[ms][ns] = __builtin_amdgcn_mfma_f32_16x16x32_f16(af[cur][ms], bf[cur][ns], acc[ms][ns], 0, 0, 0);
    }

    // ---- exp + Es + colsum partials (r0-proven epilogue)
    float colp[4] = {0.f, 0.f, 0.f, 0.f};
#pragma unroll
    for (int ms = 0; ms < 4; ++ms) {
#pragma unroll
        for (int ns = 0; ns < 4; ++ns) {
            int gc = col0 + wn + ns * 16 + lm;
            bool ok = gc < KDIM;
#pragma unroll
            for (int rr = 0; rr < 4; ++rr) {
                float e = ok ? __expf(acc[ms][ns][rr] * 20.0f) : 0.0f;
                colp[ns] += e;
                Es[wm + ms * 16 + q * 4 + rr][wn + ns * 16 + lm] = (f16)e;
            }
        }
    }
#pragma unroll
    for (int ns = 0; ns < 4; ++ns) {
        colp[ns] += __shfl_xor(colp[ns], 16, 64);
        colp[ns] += __shfl_xor(colp[ns], 32, 64);
    }
    __syncthreads();
    {
        int rr = tid >> 1, half = tid & 1;
        const f16* src = &Es[rr][half * 64];
        f16* dst = E16 + (size_t)(row0 + rr) * KPAD + col0 + half * 64;
#pragma unroll
        for (int i = 0; i < 8; ++i)
            *(uint4*)(dst + i * 8) = *(const uint4*)(src + i * 8);
    }
    __syncthreads();
    float* cred = (float*)smem;
    if (tid < 128) cred[tid] = 0.f;
    __syncthreads();
    if (lane < 16) {
#pragma unroll
        for (int ns = 0; ns < 4; ++ns)
            atomicAdd(&cred[wn + ns * 16 + lane], colp[ns]);   // LDS atomic
    }
    __syncthreads();
    if (tid < 128)
        atomicAdd(&S0sl[(size_t)(by & 7) * KPAD + col0 + tid], cred[tid]);
}

// ---------------------------------------------------------------------------
// rowpass: XCD-aligned block remap (r5-proven). gemm panel p was written by
// XCD p%8; block bid (XCD bid%8) reads strips of panels with p%8 == bid%8.
// Bijective: (x, i%12, i/12) <-> (p, st), 8*12*8 = 768.
__global__ __launch_bounds__(256)
void rowpass_k(const f16* __restrict__ E16, const float* __restrict__ SinSl,
               float* __restrict__ SoutSl) {
    __shared__ float rl[KPAD];
    __shared__ float cols4[4][KPAD];
    int tid = threadIdx.x, bid = blockIdx.x;
    {
        int n = tid * 4;
        float4 s = *(const float4*)(SinSl + n);
#pragma unroll
        for (int j = 1; j < NSLAB; ++j) {
            float4 t = *(const float4*)(SinSl + (size_t)j * KPAD + n);
            s.x += t.x; s.y += t.y; s.z += t.z; s.w += t.w;
        }
        float4 o;
        o.x = (n + 0 < KDIM) ? 1.0f / (1000.0f * s.x) : 0.0f;
        o.y = (n + 1 < KDIM) ? 1.0f / (1000.0f * s.y) : 0.0f;
        o.z = (n + 2 < KDIM) ? 1.0f / (1000.0f * s.z) : 0.0f;
        o.w = (n + 3 < KDIM) ? 1.0f / (1000.0f * s.w) : 0.0f;
        *(float4*)(rl + n) = o;
    }
    __syncthreads();
    int wave = tid >> 6, lane = tid & 63;
    int n0 = lane * 16;
    float rv[16];
#pragma unroll
    for (int i = 0; i < 16; ++i) rv[i] = rl[n0 + i];

    int x = bid & 7, ii = bid >> 3;
    int p = x + 8 * (ii % 12);            // panel [0,96), p%8 == x
    int st = ii / 12;                     // strip [0,8)
    int rowbase = p * 128 + st * 16 + wave * 4;
    const f16* erb = E16 + (size_t)rowbase * KPAD + n0;
    f16x8 e[4][2];
#pragma unroll
    for (int j = 0; j < 4; ++j) {
        e[j][0] = *(const f16x8*)(erb + (size_t)j * KPAD);
        e[j][1] = *(const f16x8*)(erb + (size_t)j * KPAD + 8);
    }
    float pr[4];
#pragma unroll
    for (int j = 0; j < 4; ++j) {
        float acc = 0.f;
#pragma unroll
        for (int i = 0; i < 8; ++i) {
            acc += (float)e[j][0][i] * rv[i];
            acc += (float)e[j][1][i] * rv[8 + i];
        }
        pr[j] = acc;
    }
#pragma unroll
    for (int m = 32; m >= 1; m >>= 1) {
        float t0 = __shfl_xor(pr[0], m, 64);
        float t1 = __shfl_xor(pr[1], m, 64);
        float t2 = __shfl_xor(pr[2], m, 64);
        float t3 = __shfl_xor(pr[3], m, 64);
        pr[0] += t0; pr[1] += t1; pr[2] += t2; pr[3] += t3;
    }
    float c[4];
#pragma unroll
    for (int j = 0; j < 4; ++j) c[j] = 1.0f / (12288.0f * pr[j]);
    float ca[16];
#pragma unroll
    for (int i = 0; i < 16; ++i) {
        int h = i >> 3, iv = i & 7;
        ca[i] = (float)e[0][h][iv] * c[0] + (float)e[1][h][iv] * c[1]
              + (float)e[2][h][iv] * c[2] + (float)e[3][h][iv] * c[3];
    }
#pragma unroll
    for (int i = 0; i < 16; ++i) {
        int idx = (i + lane) & 15;
        cols4[wave][n0 + idx] = ca[idx];
    }
    __syncthreads();
    float* outSlab = SoutSl + (size_t)x * KPAD;
    for (int n = tid; n < KPAD; n += 256)
        atomicAdd(&outSlab[n],
                  cols4[0][n] + cols4[1][n] + cols4[2][n] + cols4[3][n]);
}

// ---------------------------------------------------------------------------
// out: XCD-aligned remap over the 32 feats panels (r5-proven):
// (x, i%4, i/4) <-> (p, st), 8*4*32 = 1024 blocks, 4 rows each.
__global__ __launch_bounds__(256)
void out_k(const f16* __restrict__ E16, const float* __restrict__ S2sl,
           float* __restrict__ out) {
    __shared__ float rl[KPAD];
    int tid = threadIdx.x;
    {
        int n = tid * 4;
        float4 s = *(const float4*)(S2sl + n);
#pragma unroll
        for (int j = 1; j < NSLAB; ++j) {
            float4 t = *(const float4*)(S2sl + (size_t)j * KPAD + n);
            s.x += t.x; s.y += t.y; s.z += t.z; s.w += t.w;
        }
        float4 o;
        o.x = (n + 0 < KDIM) ? 1.0f / (1000.0f * s.x) : 0.0f;
        o.y = (n + 1 < KDIM) ? 1.0f / (1000.0f * s.y) : 0.0f;
        o.z = (n + 2 < KDIM) ? 1.0f / (1000.0f * s.z) : 0.0f;
        o.w = (n + 3 < KDIM) ? 1.0f / (1000.0f * s.w) : 0.0f;
        *(float4*)(rl + n) = o;
    }
    __syncthreads();
    int wave = tid >> 6, lane = tid & 63;
    int n0 = lane * 16;
    float rv[16];
#pragma unroll
    for (int i = 0; i < 16; ++i) rv[i] = rl[n0 + i];
    int bid = blockIdx.x;
    int x = bid & 7, ii = bid >> 3;
    int p = x + 8 * (ii % 4);             // panel [0,32), p%8 == x
    int st = ii / 4;                      // [0,32)
    int row = p * 128 + st * 4 + wave;
    const f16* er = E16 + (size_t)row * KPAD + n0;
    f16x8 e0 = *(const f16x8*)er;
    f16x8 e1 = *(const f16x8*)(er + 8);
    float w[16];
    float pv = 0.f;
#pragma unroll
    for (int i = 0; i < 8; ++i) {
        w[i] = (float)e0[i] * rv[i];
        w[8 + i] = (float)e1[i] * rv[8 + i];
    }
#pragma unroll
    for (int i = 0; i < 16; ++i) pv += w[i];
    pv = wsum(pv);
    float inv = 1.0f / pv;
    float* orow = out + (size_t)row * KDIM;
#pragma unroll
    for (int i = 0; i < 16; i += 4) {
        int n = n0 + i;
        if (n + 3 < KDIM) {   // KDIM%4==0: quad fully valid or fully out
            float4 o = { w[i] * inv, w[i + 1] * inv, w[i + 2] * inv, w[i + 3] * inv };
            *(float4*)(orow + n) = o;
        }
    }
}

// ---------------------------------------------------------------------------
extern "C" void kernel_launch(void* const* d_in, const int* in_sizes, int n_in,
                              void* d_out, int out_size, void* d_ws, size_t ws_size,
                              hipStream_t stream) {
    (void)in_sizes; (void)n_in; (void)out_size; (void)ws_size;
    const float* feats = (const float*)d_in[0];   // [4096,256]
    const float* head  = (const float*)d_in[1];   // [256,1000]
    const float* queue = (const float*)d_in[2];   // [8192,256]
    float* out = (float*)d_out;                   // [4096,1000]

    char* ws = (char*)d_ws;
    f16*   A16   = (f16*)(ws + OFF_A16);
    f16*   Bf    = (f16*)(ws + OFF_BF);
    f16*   E16   = (f16*)(ws + OFF_E16);
    float* slabs = (float*)(ws + OFF_SL);
    float* S0sl  = slabs;
    float* S1sl  = slabs + NSLAB * KPAD;
    float* S2sl  = slabs + 2 * NSLAB * KPAD;

    prep_k<<<3128, 256, 0, stream>>>(feats, queue, head, A16, Bf, slabs);
    gemm_exp_k<<<768, 256, 0, stream>>>(A16, Bf, E16, S0sl);
    rowpass_k<<<768, 256, 0, stream>>>(E16, S0sl, S1sl);
    rowpass_k<<<768, 256, 0, stream>>>(E16, S1sl, S2sl);
    out_k<<<1024, 256, 0, stream>>>(E16, S2sl, out);
}

// Round 10
// 140.877 us; speedup vs baseline: 1.6686x; 1.0448x over previous
//
#include <hip/hip_runtime.h>
#include <math.h>

typedef _Float16 f16;
typedef _Float16 f16x8 __attribute__((ext_vector_type(8)));
typedef _Float16 f16x4 __attribute__((ext_vector_type(4)));
typedef float f32x4 __attribute__((ext_vector_type(4)));

#define NROWS 12288
#define NFEAT 4096
#define DDIM  256
#define KDIM  1000
#define KPAD  1024
#define NSLAB 8

// workspace layout (bytes)
static const size_t OFF_BF  = 0;          // 1024*256 f16  =    524,288
static const size_t OFF_E16 = 524288;     // 12288*1024 f16= 25,165,824
static const size_t OFF_SL  = 25690112;   // 3 * 8 * 1024 f32 slabs

__device__ inline float wsum(float v) {
#pragma unroll
    for (int m = 32; m >= 1; m >>= 1) v += __shfl_xor(v, m, 64);
    return v;
}

// panel byte address (row stride 64 B) with bank swizzle; bijective,
// 16B-alignment preserving (XORs bits 4..6 only).
__device__ __forceinline__ int psw(int row, int bytecol) {
    return (row * 64 + bytecol) ^ ((row & 7) << 4);
}

// ---------------------------------------------------------------------------
// prep (56 blocks): [0,32)  head -> transposed normalized f16 Bf (8 k/block)
//                   [32,56) zero the 3 colsum slab sets
__global__ __launch_bounds__(256)
void prep_k(const float* __restrict__ head, f16* __restrict__ Bf,
            float* __restrict__ slabs) {
    int b = blockIdx.x, tid = threadIdx.x;
    int wave = tid >> 6, lane = tid & 63;
    if (b < 32) {
        __shared__ float rin[8];
        int kb = b * 8;
        for (int j = 0; j < 2; ++j) {
            int k = kb + wave * 2 + j;
            const float* hr = head + (size_t)k * KDIM;
            float s = 0.f;
            for (int n = lane; n < KDIM; n += 64) { float v = hr[n]; s += v * v; }
            s = wsum(s);
            if (lane == 0) rin[wave * 2 + j] = 1.0f / sqrtf(fmaxf(s, 1e-24f));
        }
        __syncthreads();
        float r[8];
#pragma unroll
        for (int i = 0; i < 8; ++i) r[i] = rin[i];
        for (int n = tid; n < KDIM; n += 256) {
            f16 tmp[8];
#pragma unroll
            for (int i = 0; i < 8; ++i)
                tmp[i] = (f16)(head[(size_t)(kb + i) * KDIM + n] * r[i]);
            *(uint4*)(Bf + (size_t)n * DDIM + kb) = *(const uint4*)(tmp);
        }
    } else {
        float* dst = slabs + (size_t)(b - 32) * KPAD + tid * 4;
        *(float4*)dst = make_float4(0.f, 0.f, 0.f, 0.f);
    }
}

// ---------------------------------------------------------------------------
// MFMA GEMM, A read RAW from feats/queue f32 with COALESCED staging
// (thread -> row s*32+(tid>>3), cols (tid&7)*4: wave = 8x128B contiguous
// segments). Row normalization commutes with the dot product, so it is
// folded into the epilogue: sumsq accumulates as a by-product of staging
// loads (same data, no prepass), and exp applies acc * (20*rinv_row).
// XCD swizzle by=b%96 (a panel's 8 blocks share b%8 -> one XCD L2 copy;
// proven r4: FETCH 48->8.4 MB). This is the session-best (r5, 139.9 us)
// configuration, restored after the zero-barrier/register-dbuf line
// (r7-r9) was falsified: spills at any occupancy tier with f32 carrying,
// neutral with f16 operands -- TLP at 16 waves/CU already hides the
// staged-load latency, so the per-tile barrier is not the limiter.
__global__ __launch_bounds__(256, 3)
void gemm_exp_k(const float* __restrict__ feats, const float* __restrict__ queue,
                const f16* __restrict__ Bf, f16* __restrict__ E16,
                float* __restrict__ S0sl) {
    __shared__ __align__(16) char smem[35328];
    f16 (*Es)[136] = (f16(*)[136])smem;
    float* rinvl = (float*)(smem + 34816);
    const int tid = threadIdx.x;
    const int wave = tid >> 6, lane = tid & 63;
    const int lm = lane & 15, q = lane >> 4;
    const int b = blockIdx.x;
    const int by = b % 96, bx = b / 96;        // XCD-locality swizzle
    const int row0 = by * 128, col0 = bx * 128;
    const int wm = (wave >> 1) * 64, wn = (wave & 1) * 64;

    // staging assignment: sweep s -> row s*32+(tid>>3), float4 at col (tid&7)*4
    const float* rowptr[4];
#pragma unroll
    for (int s = 0; s < 4; ++s) {
        int grow = row0 + s * 32 + (tid >> 3);
        rowptr[s] = (grow < NFEAT) ? feats + (size_t)grow * DDIM
                                   : queue + (size_t)(grow - NFEAT) * DDIM;
    }
    float ss[4] = {0.f, 0.f, 0.f, 0.f};

    auto stage = [&](int tt, int buf) {
        char* P = smem + buf * 8192;
#pragma unroll
        for (int s = 0; s < 4; ++s) {
            float4 v = *(const float4*)(rowptr[s] + tt * 32 + (tid & 7) * 4);
            ss[s] += v.x * v.x + v.y * v.y + v.z * v.z + v.w * v.w;
            f16x4 tmp = { (f16)v.x, (f16)v.y, (f16)v.z, (f16)v.w };
            *(f16x4*)(P + psw(s * 32 + (tid >> 3), (tid & 7) * 8)) = tmp;
        }
    };

    const f16* Bb = Bf + (size_t)(col0 + wn + lm) * DDIM + q * 8;

    f32x4 acc[4][4];
#pragma unroll
    for (int i = 0; i < 4; ++i)
#pragma unroll
        for (int j = 0; j < 4; ++j) acc[i][j] = (f32x4){0.f, 0.f, 0.f, 0.f};

    stage(0, 0);
    __syncthreads();

    // K loop, double-buffered panels (1 barrier per tile). Hazard: stage(t+1)
    // overwrites the buffer last read in iter t-1, whose reads completed at
    // iter t-1's barrier.
#pragma unroll
    for (int t = 0; t < 8; ++t) {
        char* PA = smem + (t & 1) * 8192;
        f16x8 a[4], bfr[4];
#pragma unroll
        for (int ms = 0; ms < 4; ++ms)
            a[ms] = *(const f16x8*)(PA + psw(wm + ms * 16 + lm, q * 16));
#pragma unroll
        for (int ns = 0; ns < 4; ++ns)
            bfr[ns] = *(const f16x8*)(Bb + (size_t)ns * 16 * DDIM + t * 32);
        if (t < 7) stage(t + 1, (t + 1) & 1);
        __syncthreads();
#pragma unroll
        for (int ms = 0; ms < 4; ++ms)
#pragma unroll
            for (int ns = 0; ns < 4; ++ns)
                acc[ms][ns] = __builtin_amdgcn_mfma_f32_16x16x32_f16(a[ms], bfr[ns], acc[ms][ns], 0, 0, 0);
    }
    // all panel ds_reads completed before iter-7's barrier; Es may reuse smem.

    // ---- row inverse norms from staged sumsq: reduce over the 8 lanes
    // sharing a row (lane^1,2,4), write rinvl[128]
#pragma unroll
    for (int m = 1; m <= 4; m <<= 1) {
        ss[0] += __shfl_xor(ss[0], m, 64);
        ss[1] += __shfl_xor(ss[1], m, 64);
        ss[2] += __shfl_xor(ss[2], m, 64);
        ss[3] += __shfl_xor(ss[3], m, 64);
    }
    if ((lane & 7) == 0) {
#pragma unroll
        for (int s = 0; s < 4; ++s)
            rinvl[s * 32 + (tid >> 3)] = 1.0f / sqrtf(fmaxf(ss[s], 1e-24f));
    }
    __syncthreads();

    float rsc[4][4];
#pragma unroll
    for (int ms = 0; ms < 4; ++ms)
#pragma unroll
        for (int rr = 0; rr < 4; ++rr)
            rsc[ms][rr] = 20.0f * rinvl[wm + ms * 16 + q * 4 + rr];

    // ---- exp + Es + colsum partials (proven epilogue; scale per-row)
    float colp[4] = {0.f, 0.f, 0.f, 0.f};
#pragma unroll
    for (int ms = 0; ms < 4; ++ms) {
#pragma unroll
        for (int ns = 0; ns < 4; ++ns) {
            int gc = col0 + wn + ns * 16 + lm;
            bool ok = gc < KDIM;
#pragma unroll
            for (int rr = 0; rr < 4; ++rr) {
                float e = ok ? __expf(acc[ms][ns][rr] * rsc[ms][rr]) : 0.0f;
                colp[ns] += e;
                Es[wm + ms * 16 + q * 4 + rr][wn + ns * 16 + lm] = (f16)e;
            }
        }
    }
#pragma unroll
    for (int ns = 0; ns < 4; ++ns) {
        colp[ns] += __shfl_xor(colp[ns], 16, 64);
        colp[ns] += __shfl_xor(colp[ns], 32, 64);
    }
    __syncthreads();
    {
        int rr = tid >> 1, half = tid & 1;
        const f16* src = &Es[rr][half * 64];
        f16* dst = E16 + (size_t)(row0 + rr) * KPAD + col0 + half * 64;
#pragma unroll
        for (int i = 0; i < 8; ++i)
            *(uint4*)(dst + i * 8) = *(const uint4*)(src + i * 8);
    }
    __syncthreads();
    float* cred = (float*)smem;
    if (tid < 128) cred[tid] = 0.f;
    __syncthreads();
    if (lane < 16) {
#pragma unroll
        for (int ns = 0; ns < 4; ++ns)
            atomicAdd(&cred[wn + ns * 16 + lane], colp[ns]);   // LDS atomic
    }
    __syncthreads();
    if (tid < 128)
        atomicAdd(&S0sl[(size_t)(by & 7) * KPAD + col0 + tid], cred[tid]);
}

// ---------------------------------------------------------------------------
// rowpass: XCD-aligned block remap. gemm panel p was written by XCD p%8;
// block bid (XCD bid%8) reads strip st of a panel p with p%8 == bid%8, so
// E reads hit the local L2 instead of crossing XCDs. Bijective:
// (x, i%12, i/12) <-> (p, st), 8*12*8 = 768.
__global__ __launch_bounds__(256)
void rowpass_k(const f16* __restrict__ E16, const float* __restrict__ SinSl,
               float* __restrict__ SoutSl) {
    __shared__ float rl[KPAD];
    __shared__ float cols4[4][KPAD];
    int tid = threadIdx.x, bid = blockIdx.x;
    {
        int n = tid * 4;
        float4 s = *(const float4*)(SinSl + n);
#pragma unroll
        for (int j = 1; j < NSLAB; ++j) {
            float4 t = *(const float4*)(SinSl + (size_t)j * KPAD + n);
            s.x += t.x; s.y += t.y; s.z += t.z; s.w += t.w;
        }
        float4 o;
        o.x = (n + 0 < KDIM) ? 1.0f / (1000.0f * s.x) : 0.0f;
        o.y = (n + 1 < KDIM) ? 1.0f / (1000.0f * s.y) : 0.0f;
        o.z = (n + 2 < KDIM) ? 1.0f / (1000.0f * s.z) : 0.0f;
        o.w = (n + 3 < KDIM) ? 1.0f / (1000.0f * s.w) : 0.0f;
        *(float4*)(rl + n) = o;
    }
    __syncthreads();
    int wave = tid >> 6, lane = tid & 63;
    int n0 = lane * 16;
    float rv[16];
#pragma unroll
    for (int i = 0; i < 16; ++i) rv[i] = rl[n0 + i];

    int x = bid & 7, ii = bid >> 3;
    int p = x + 8 * (ii % 12);            // panel [0,96), p%8 == x
    int st = ii / 12;                     // strip [0,8)
    int rowbase = p * 128 + st * 16 + wave * 4;
    const f16* erb = E16 + (size_t)rowbase * KPAD + n0;
    f16x8 e[4][2];
#pragma unroll
    for (int j = 0; j < 4; ++j) {
        e[j][0] = *(const f16x8*)(erb + (size_t)j * KPAD);
        e[j][1] = *(const f16x8*)(erb + (size_t)j * KPAD + 8);
    }
    float pr[4];
#pragma unroll
    for (int j = 0; j < 4; ++j) {
        float acc = 0.f;
#pragma unroll
        for (int i = 0; i < 8; ++i) {
            acc += (float)e[j][0][i] * rv[i];
            acc += (float)e[j][1][i] * rv[8 + i];
        }
        pr[j] = acc;
    }
#pragma unroll
    for (int m = 32; m >= 1; m >>= 1) {
        float t0 = __shfl_xor(pr[0], m, 64);
        float t1 = __shfl_xor(pr[1], m, 64);
        float t2 = __shfl_xor(pr[2], m, 64);
        float t3 = __shfl_xor(pr[3], m, 64);
        pr[0] += t0; pr[1] += t1; pr[2] += t2; pr[3] += t3;
    }
    float c[4];
#pragma unroll
    for (int j = 0; j < 4; ++j) c[j] = 1.0f / (12288.0f * pr[j]);
    float ca[16];
#pragma unroll
    for (int i = 0; i < 16; ++i) {
        int h = i >> 3, iv = i & 7;
        ca[i] = (float)e[0][h][iv] * c[0] + (float)e[1][h][iv] * c[1]
              + (float)e[2][h][iv] * c[2] + (float)e[3][h][iv] * c[3];
    }
#pragma unroll
    for (int i = 0; i < 16; ++i) {
        int idx = (i + lane) & 15;
        cols4[wave][n0 + idx] = ca[idx];
    }
    __syncthreads();
    float* outSlab = SoutSl + (size_t)x * KPAD;
    for (int n = tid; n < KPAD; n += 256)
        atomicAdd(&outSlab[n],
                  cols4[0][n] + cols4[1][n] + cols4[2][n] + cols4[3][n]);
}

// ---------------------------------------------------------------------------
// out: XCD-aligned remap over the 32 feats panels: (x, i%4, i/4) <-> (p, st),
// 8*4*32 = 1024 blocks, 4 rows each.
__global__ __launch_bounds__(256)
void out_k(const f16* __restrict__ E16, const float* __restrict__ S2sl,
           float* __restrict__ out) {
    __shared__ float rl[KPAD];
    int tid = threadIdx.x;
    {
        int n = tid * 4;
        float4 s = *(const float4*)(S2sl + n);
#pragma unroll
        for (int j = 1; j < NSLAB; ++j) {
            float4 t = *(const float4*)(S2sl + (size_t)j * KPAD + n);
            s.x += t.x; s.y += t.y; s.z += t.z; s.w += t.w;
        }
        float4 o;
        o.x = (n + 0 < KDIM) ? 1.0f / (1000.0f * s.x) : 0.0f;
        o.y = (n + 1 < KDIM) ? 1.0f / (1000.0f * s.y) : 0.0f;
        o.z = (n + 2 < KDIM) ? 1.0f / (1000.0f * s.z) : 0.0f;
        o.w = (n + 3 < KDIM) ? 1.0f / (1000.0f * s.w) : 0.0f;
        *(float4*)(rl + n) = o;
    }
    __syncthreads();
    int wave = tid >> 6, lane = tid & 63;
    int n0 = lane * 16;
    float rv[16];
#pragma unroll
    for (int i = 0; i < 16; ++i) rv[i] = rl[n0 + i];
    int bid = blockIdx.x;
    int x = bid & 7, ii = bid >> 3;
    int p = x + 8 * (ii % 4);             // panel [0,32), p%8 == x
    int st = ii / 4;                      // [0,32)
    int row = p * 128 + st * 4 + wave;
    const f16* er = E16 + (size_t)row * KPAD + n0;
    f16x8 e0 = *(const f16x8*)er;
    f16x8 e1 = *(const f16x8*)(er + 8);
    float w[16];
    float pv = 0.f;
#pragma unroll
    for (int i = 0; i < 8; ++i) {
        w[i] = (float)e0[i] * rv[i];
        w[8 + i] = (float)e1[i] * rv[8 + i];
    }
#pragma unroll
    for (int i = 0; i < 16; ++i) pv += w[i];
    pv = wsum(pv);
    float inv = 1.0f / pv;
    float* orow = out + (size_t)row * KDIM;
#pragma unroll
    for (int i = 0; i < 16; i += 4) {
        int n = n0 + i;
        if (n + 3 < KDIM) {   // KDIM%4==0: quad fully valid or fully out
            float4 o = { w[i] * inv, w[i + 1] * inv, w[i + 2] * inv, w[i + 3] * inv };
            *(float4*)(orow + n) = o;
        }
    }
}

// ---------------------------------------------------------------------------
extern "C" void kernel_launch(void* const* d_in, const int* in_sizes, int n_in,
                              void* d_out, int out_size, void* d_ws, size_t ws_size,
                              hipStream_t stream) {
    (void)in_sizes; (void)n_in; (void)out_size; (void)ws_size;
    const float* feats = (const float*)d_in[0];   // [4096,256]
    const float* head  = (const float*)d_in[1];   // [256,1000]
    const float* queue = (const float*)d_in[2];   // [8192,256]
    float* out = (float*)d_out;                   // [4096,1000]

    char* ws = (char*)d_ws;
    f16*   Bf    = (f16*)(ws + OFF_BF);
    f16*   E16   = (f16*)(ws + OFF_E16);
    float* slabs = (float*)(ws + OFF_SL);
    float* S0sl  = slabs;
    float* S1sl  = slabs + NSLAB * KPAD;
    float* S2sl  = slabs + 2 * NSLAB * KPAD;

    prep_k<<<56, 256, 0, stream>>>(head, Bf, slabs);
    gemm_exp_k<<<768, 256, 0, stream>>>(feats, queue, Bf, E16, S0sl);
    rowpass_k<<<768, 256, 0, stream>>>(E16, S0sl, S1sl);
    rowpass_k<<<768, 256, 0, stream>>>(E16, S1sl, S2sl);
    out_k<<<1024, 256, 0, stream>>>(E16, S2sl, out);
}